// Round 1
// baseline (889.598 us; speedup 1.0000x reference)
//
#include <hip/hip_runtime.h>
#include <hip/hip_bf16.h>
#include <stdint.h>

#define S_LEN 2048
#define HDIM  2048
#define NH    16
#define HD    128
#define BATCH 4

typedef __attribute__((ext_vector_type(8))) short bf16x8;
typedef __attribute__((ext_vector_type(4))) float f32x4;
typedef __attribute__((ext_vector_type(4))) float float4v;
typedef __attribute__((ext_vector_type(4))) unsigned short u16x4;

__device__ __forceinline__ void gload_lds16(const void* g, void* l) {
  __builtin_amdgcn_global_load_lds(
      (const __attribute__((address_space(1))) unsigned int*)g,
      (__attribute__((address_space(3))) unsigned int*)l,
      16, 0, 0);
}

__device__ __forceinline__ unsigned short f2bf(float x) {
  __hip_bfloat16 b = __float2bfloat16(x);
  return *reinterpret_cast<unsigned short*>(&b);
}

// ---------------- fp32 -> bf16 convert ----------------
__global__ __launch_bounds__(256) void cvt_kernel(const float* __restrict__ in,
                                                  unsigned short* __restrict__ out,
                                                  int n4) {
  int stride = gridDim.x * blockDim.x;
  for (int i = blockIdx.x * blockDim.x + threadIdx.x; i < n4; i += stride) {
    float4v v = *(const float4v*)(in + (size_t)i * 4);
    u16x4 o;
    o.x = f2bf(v.x); o.y = f2bf(v.y); o.z = f2bf(v.z); o.w = f2bf(v.w);
    *(u16x4*)(out + (size_t)i * 4) = o;
  }
}

// ---------------- GEMM: C[M,N] = A[M,K] * B[N,K]^T + bias ----------------
// m97 structure: 128x128 tile, BK=64, 4 waves (2x2 of 64x64), global_load_lds.
template<int OUTF32>
__global__ __launch_bounds__(256, 2) void gemm_bt(
    const __hip_bfloat16* __restrict__ A, const __hip_bfloat16* __restrict__ B,
    const float* __restrict__ bias, void* __restrict__ C,
    int M, int N, int K) {
  __shared__ char lds[32768];  // As[128][64] bf16 | Bs[128][64] bf16
  const int tid  = threadIdx.x;
  const int w    = tid >> 6;
  const int lane = tid & 63;
  const int g    = lane >> 4;
  const int ln   = lane & 15;
  const int bm = blockIdx.y, bn = blockIdx.x;
  const int wm = (w >> 1) * 64, wn = (w & 1) * 64;

  f32x4 acc[4][4];
#pragma unroll
  for (int m = 0; m < 4; m++)
#pragma unroll
    for (int n = 0; n < 4; n++) acc[m][n] = (f32x4){0.f, 0.f, 0.f, 0.f};

  const int r8  = lane >> 3;        // row within 8-row group
  const int c16 = (lane & 7) * 16;  // byte offset along k
  const char* gA = (const char*)A + (size_t)(bm * 128 + w * 32 + r8) * K * 2 + c16;
  const char* gB = (const char*)B + (size_t)(bn * 128 + w * 32 + r8) * K * 2 + c16;
  char* lA = lds + (w * 32) * 128;
  char* lB = lds + 16384 + (w * 32) * 128;

  for (int k0 = 0; k0 < K; k0 += 64) {
#pragma unroll
    for (int i = 0; i < 4; i++) {
      gload_lds16(gA + (size_t)i * 8 * K * 2 + (size_t)k0 * 2, lA + i * 8 * 128);
      gload_lds16(gB + (size_t)i * 8 * K * 2 + (size_t)k0 * 2, lB + i * 8 * 128);
    }
    __syncthreads();
#pragma unroll
    for (int kk = 0; kk < 2; kk++) {
      bf16x8 af[4], bfr[4];
#pragma unroll
      for (int m = 0; m < 4; m++)
        af[m] = *(const bf16x8*)(lds + (wm + m * 16 + ln) * 128 + kk * 64 + g * 16);
#pragma unroll
      for (int n = 0; n < 4; n++)
        bfr[n] = *(const bf16x8*)(lds + 16384 + (wn + n * 16 + ln) * 128 + kk * 64 + g * 16);
#pragma unroll
      for (int m = 0; m < 4; m++)
#pragma unroll
        for (int n = 0; n < 4; n++)
          acc[m][n] = __builtin_amdgcn_mfma_f32_16x16x32_bf16(af[m], bfr[n], acc[m][n], 0, 0, 0);
    }
    __syncthreads();
  }

#pragma unroll
  for (int n = 0; n < 4; n++) {
    const int col = bn * 128 + wn + n * 16 + ln;
    const float bv = bias[col];
#pragma unroll
    for (int m = 0; m < 4; m++) {
      const int row0 = bm * 128 + wm + m * 16 + g * 4;
#pragma unroll
      for (int r = 0; r < 4; r++) {
        float v = acc[m][n][r] + bv;
        if (OUTF32)
          ((float*)C)[(size_t)(row0 + r) * N + col] = v;
        else
          ((__hip_bfloat16*)C)[(size_t)(row0 + r) * N + col] = __float2bfloat16(v);
      }
    }
  }
}

// ---------------- V[b,s,h,d] -> Vt[b,h,d,s] ----------------
__global__ __launch_bounds__(256) void transpose_v(const __hip_bfloat16* __restrict__ V,
                                                   __hip_bfloat16* __restrict__ Vt) {
  __shared__ unsigned short t[64 * 132];  // [s][d] padded
  const int tid = threadIdx.x;
  const int bh = blockIdx.y;
  const int b = bh >> 4, h = bh & 15;
  const int s0 = blockIdx.x * 64;
  const unsigned short* Vp = (const unsigned short*)V + (size_t)b * S_LEN * HDIM + h * HD;
#pragma unroll
  for (int i = 0; i < 4; i++) {
    int idx = i * 256 + tid;
    int s = idx >> 4, c = idx & 15;
    const uint64_t* src = (const uint64_t*)(Vp + (size_t)(s0 + s) * HDIM + c * 8);
    uint64_t v0 = src[0], v1 = src[1];
    uint64_t* dst = (uint64_t*)&t[s * 132 + c * 8];
    dst[0] = v0; dst[1] = v1;
  }
  __syncthreads();
  unsigned short* Vtp = (unsigned short*)Vt + (size_t)bh * HD * S_LEN;
#pragma unroll
  for (int i = 0; i < 8; i++) {
    int idx = i * 256 + tid;
    int d = idx >> 4, sc = idx & 15;
    u16x4 vv;
    vv.x = t[(sc * 4 + 0) * 132 + d];
    vv.y = t[(sc * 4 + 1) * 132 + d];
    vv.z = t[(sc * 4 + 2) * 132 + d];
    vv.w = t[(sc * 4 + 3) * 132 + d];
    *(u16x4*)(Vtp + (size_t)d * S_LEN + s0 + sc * 4) = vv;
  }
}

// ---------------- causal flash attention ----------------
// Q,K: [B,S,H] bf16 (H = nh*hd).  Vt: [B*nh, hd, S] bf16.  O: [B,S,H] bf16.
#define ATT_SCALE 0.08838834764831845f
#define L2E 1.4426950408889634f

__global__ __launch_bounds__(256, 2) void attn_kernel(
    const __hip_bfloat16* __restrict__ Q, const __hip_bfloat16* __restrict__ Kt,
    const __hip_bfloat16* __restrict__ Vt, __hip_bfloat16* __restrict__ O) {
  __shared__ char plds[16384];  // 4 waves x [32 q][64 key] bf16, XOR-swizzled
  const int tid = threadIdx.x;
  const int w = tid >> 6;
  const int lane = tid & 63;
  const int g = lane >> 4;
  const int ln = lane & 15;
  const int qt = 15 - blockIdx.x;   // large q-tiles (most work) dispatched first
  const int bh = blockIdx.y;
  const int b = bh >> 4, h = bh & 15;
  const int q0 = qt * 128 + w * 32;  // this wave's first q row

  const char* Qb = (const char*)Q + ((size_t)b * S_LEN * HDIM + h * HD) * 2;
  const char* Kb = (const char*)Kt + ((size_t)b * S_LEN * HDIM + h * HD) * 2;
  const char* Vb = (const char*)Vt + ((size_t)bh * HD * S_LEN) * 2;
  char* pw = plds + w * 4096;

  // Q fragments in registers: qf[qs][dc] covers rows q0+qs*16+ln, d = dc*32+g*8..+7
  bf16x8 qf[2][4];
#pragma unroll
  for (int qs = 0; qs < 2; qs++)
#pragma unroll
    for (int dc = 0; dc < 4; dc++)
      qf[qs][dc] = *(const bf16x8*)(Qb + (size_t)(q0 + qs * 16 + ln) * HDIM * 2 +
                                    (dc * 32 + g * 8) * 2);

  f32x4 o[2][8];
#pragma unroll
  for (int qs = 0; qs < 2; qs++)
#pragma unroll
    for (int ds = 0; ds < 8; ds++) o[qs][ds] = (f32x4){0.f, 0.f, 0.f, 0.f};
  float mrun[2][4], lrun[2][4];
#pragma unroll
  for (int qs = 0; qs < 2; qs++)
#pragma unroll
    for (int r = 0; r < 4; r++) { mrun[qs][r] = -__builtin_inff(); lrun[qs][r] = 0.f; }

  const int ntiles = (q0 + 95) >> 6;  // kv tiles needed by this wave (causal)
  for (int t = 0; t < ntiles; t++) {
    const int kv0 = t * 64;
    // ---- S = Q K^T ----
    f32x4 sa[2][4];
#pragma unroll
    for (int qs = 0; qs < 2; qs++)
#pragma unroll
      for (int ks = 0; ks < 4; ks++) sa[qs][ks] = (f32x4){0.f, 0.f, 0.f, 0.f};
#pragma unroll
    for (int dc = 0; dc < 4; dc++) {
      bf16x8 kf[4];
#pragma unroll
      for (int ks = 0; ks < 4; ks++)
        kf[ks] = *(const bf16x8*)(Kb + (size_t)(kv0 + ks * 16 + ln) * HDIM * 2 +
                                  (dc * 32 + g * 8) * 2);
#pragma unroll
      for (int qs = 0; qs < 2; qs++)
#pragma unroll
        for (int ks = 0; ks < 4; ks++)
          sa[qs][ks] = __builtin_amdgcn_mfma_f32_16x16x32_bf16(qf[qs][dc], kf[ks], sa[qs][ks], 0, 0, 0);
    }
    // ---- scale + causal mask ----
    const bool needmask = (kv0 + 63) > q0;
#pragma unroll
    for (int qs = 0; qs < 2; qs++)
#pragma unroll
      for (int ks = 0; ks < 4; ks++)
#pragma unroll
        for (int r = 0; r < 4; r++) {
          float s = sa[qs][ks][r] * ATT_SCALE;
          if (needmask && (kv0 + ks * 16 + ln) > (q0 + qs * 16 + g * 4 + r))
            s = -__builtin_inff();
          sa[qs][ks][r] = s;
        }
    // ---- online softmax ----
    float alpha[2][4];
#pragma unroll
    for (int qs = 0; qs < 2; qs++)
#pragma unroll
      for (int r = 0; r < 4; r++) {
        float mx = fmaxf(fmaxf(sa[qs][0][r], sa[qs][1][r]), fmaxf(sa[qs][2][r], sa[qs][3][r]));
        mx = fmaxf(mx, __shfl_xor(mx, 1));
        mx = fmaxf(mx, __shfl_xor(mx, 2));
        mx = fmaxf(mx, __shfl_xor(mx, 4));
        mx = fmaxf(mx, __shfl_xor(mx, 8));
        float mnew = fmaxf(mrun[qs][r], mx);
        alpha[qs][r] = exp2f((mrun[qs][r] - mnew) * L2E);
        mrun[qs][r] = mnew;
      }
    float rsum[2][4];
#pragma unroll
    for (int qs = 0; qs < 2; qs++)
#pragma unroll
      for (int r = 0; r < 4; r++) rsum[qs][r] = 0.f;
#pragma unroll
    for (int qs = 0; qs < 2; qs++)
#pragma unroll
      for (int ks = 0; ks < 4; ks++)
#pragma unroll
        for (int r = 0; r < 4; r++) {
          float p = exp2f((sa[qs][ks][r] - mrun[qs][r]) * L2E);
          sa[qs][ks][r] = p;
          rsum[qs][r] += p;
        }
#pragma unroll
    for (int qs = 0; qs < 2; qs++)
#pragma unroll
      for (int r = 0; r < 4; r++) {
        float rs = rsum[qs][r];
        rs += __shfl_xor(rs, 1);
        rs += __shfl_xor(rs, 2);
        rs += __shfl_xor(rs, 4);
        rs += __shfl_xor(rs, 8);
        lrun[qs][r] = lrun[qs][r] * alpha[qs][r] + rs;
      }
    // ---- rescale O ----
#pragma unroll
    for (int qs = 0; qs < 2; qs++)
#pragma unroll
      for (int ds = 0; ds < 8; ds++)
#pragma unroll
        for (int r = 0; r < 4; r++) o[qs][ds][r] *= alpha[qs][r];
    // ---- P -> LDS (bf16, XOR swizzle: chunk ^= row&7) ----
#pragma unroll
    for (int qs = 0; qs < 2; qs++)
#pragma unroll
      for (int ks = 0; ks < 4; ks++)
#pragma unroll
        for (int r = 0; r < 4; r++) {
          int row = qs * 16 + g * 4 + r;
          int key = ks * 16 + ln;
          *(__hip_bfloat16*)(pw + row * 128 + (((key >> 3) ^ (row & 7)) << 4) + (key & 7) * 2) =
              __float2bfloat16(sa[qs][ks][r]);
        }
    // ---- O += P V ----
#pragma unroll
    for (int kk = 0; kk < 2; kk++) {
      bf16x8 pa[2];
#pragma unroll
      for (int qs = 0; qs < 2; qs++) {
        int row = qs * 16 + ln;
        pa[qs] = *(const bf16x8*)(pw + row * 128 + (((kk * 4 + g) ^ (row & 7)) << 4));
      }
#pragma unroll
      for (int ds = 0; ds < 8; ds++) {
        bf16x8 vf = *(const bf16x8*)(Vb + (size_t)(ds * 16 + ln) * S_LEN * 2 +
                                     (kv0 + kk * 32 + g * 8) * 2);
#pragma unroll
        for (int qs = 0; qs < 2; qs++)
          o[qs][ds] = __builtin_amdgcn_mfma_f32_16x16x32_bf16(pa[qs], vf, o[qs][ds], 0, 0, 0);
      }
    }
  }
  // ---- epilogue ----
  float inv[2][4];
#pragma unroll
  for (int qs = 0; qs < 2; qs++)
#pragma unroll
    for (int r = 0; r < 4; r++) inv[qs][r] = 1.0f / lrun[qs][r];
  __hip_bfloat16* Ob = O + (size_t)b * S_LEN * HDIM + h * HD;
#pragma unroll
  for (int qs = 0; qs < 2; qs++)
#pragma unroll
    for (int ds = 0; ds < 8; ds++)
#pragma unroll
      for (int r = 0; r < 4; r++)
        Ob[(size_t)(q0 + qs * 16 + g * 4 + r) * HDIM + ds * 16 + ln] =
            __float2bfloat16(o[qs][ds][r] * inv[qs][r]);
}

extern "C" void kernel_launch(void* const* d_in, const int* in_sizes, int n_in,
                              void* d_out, int out_size, void* d_ws, size_t ws_size,
                              hipStream_t stream) {
  const float* X  = (const float*)d_in[0];
  const float* Wq = (const float*)d_in[2];
  const float* bq = (const float*)d_in[3];
  const float* Wk = (const float*)d_in[4];
  const float* bk = (const float*)d_in[5];
  const float* Wv = (const float*)d_in[6];
  const float* bv = (const float*)d_in[7];
  const float* Wo = (const float*)d_in[8];
  const float* bo = (const float*)d_in[9];

  char* ws = (char*)d_ws;
  __hip_bfloat16* Xb   = (__hip_bfloat16*)(ws);                 // 32 MB
  __hip_bfloat16* Wqb  = (__hip_bfloat16*)(ws + 33554432);      // 8 MB
  __hip_bfloat16* Wkb  = (__hip_bfloat16*)(ws + 41943040);      // 8 MB
  __hip_bfloat16* Wvb  = (__hip_bfloat16*)(ws + 50331648);      // 8 MB
  __hip_bfloat16* Wob  = (__hip_bfloat16*)(ws + 58720256);      // 8 MB
  __hip_bfloat16* Qb   = (__hip_bfloat16*)(ws + 67108864);      // 32 MB
  __hip_bfloat16* Kb   = (__hip_bfloat16*)(ws + 100663296);     // 32 MB
  __hip_bfloat16* Vbuf = (__hip_bfloat16*)(ws + 134217728);     // 32 MB (reused as attn out)
  __hip_bfloat16* Vtb  = (__hip_bfloat16*)(ws + 167772160);     // 32 MB -> total 192 MB
  __hip_bfloat16* Ob   = Vbuf;

  cvt_kernel<<<2048, 256, 0, stream>>>(X,  (unsigned short*)Xb,  16777216 / 4);
  cvt_kernel<<<512,  256, 0, stream>>>(Wq, (unsigned short*)Wqb, 4194304 / 4);
  cvt_kernel<<<512,  256, 0, stream>>>(Wk, (unsigned short*)Wkb, 4194304 / 4);
  cvt_kernel<<<512,  256, 0, stream>>>(Wv, (unsigned short*)Wvb, 4194304 / 4);
  cvt_kernel<<<512,  256, 0, stream>>>(Wo, (unsigned short*)Wob, 4194304 / 4);

  dim3 gg(16, 64);  // (N/128, M/128)
  gemm_bt<0><<<gg, 256, 0, stream>>>(Xb, Wqb, bq, Qb,   8192, 2048, 2048);
  gemm_bt<0><<<gg, 256, 0, stream>>>(Xb, Wkb, bk, Kb,   8192, 2048, 2048);
  gemm_bt<0><<<gg, 256, 0, stream>>>(Xb, Wvb, bv, Vbuf, 8192, 2048, 2048);

  transpose_v<<<dim3(32, 64), 256, 0, stream>>>(Vbuf, Vtb);

  attn_kernel<<<dim3(16, 64), 256, 0, stream>>>(Qb, Kb, Vtb, Ob);

  gemm_bt<1><<<gg, 256, 0, stream>>>(Ob, Wob, bo, (float*)d_out, 8192, 2048, 2048);
}

// Round 2
// 779.520 us; speedup vs baseline: 1.1412x; 1.1412x over previous
//
#include <hip/hip_runtime.h>
#include <hip/hip_bf16.h>
#include <stdint.h>

#define S_LEN 2048
#define HDIM  2048
#define NH    16
#define HD    128
#define BATCH 4

typedef __attribute__((ext_vector_type(8))) short bf16x8;
typedef __attribute__((ext_vector_type(4))) float f32x4;
typedef __attribute__((ext_vector_type(4))) float float4v;
typedef __attribute__((ext_vector_type(4))) unsigned short u16x4;

__device__ __forceinline__ void gload_lds16(const void* g, void* l) {
  __builtin_amdgcn_global_load_lds(
      (const __attribute__((address_space(1))) unsigned int*)g,
      (__attribute__((address_space(3))) unsigned int*)l,
      16, 0, 0);
}

__device__ __forceinline__ unsigned short f2bf(float x) {
  __hip_bfloat16 b = __float2bfloat16(x);
  return *reinterpret_cast<unsigned short*>(&b);
}

// ---------------- fp32 -> bf16 convert ----------------
__global__ __launch_bounds__(256) void cvt_kernel(const float* __restrict__ in,
                                                  unsigned short* __restrict__ out,
                                                  int n4) {
  int stride = gridDim.x * blockDim.x;
  for (int i = blockIdx.x * blockDim.x + threadIdx.x; i < n4; i += stride) {
    float4v v = *(const float4v*)(in + (size_t)i * 4);
    u16x4 o;
    o.x = f2bf(v.x); o.y = f2bf(v.y); o.z = f2bf(v.z); o.w = f2bf(v.w);
    *(u16x4*)(out + (size_t)i * 4) = o;
  }
}

// ---------------- GEMM: C[M,N] = A[M,K] * B[N,K]^T + bias ----------------
// m97 structure: 128x128 tile, BK=64, 4 waves (2x2 of 64x64), global_load_lds.
template<int OUTF32>
__global__ __launch_bounds__(256, 2) void gemm_bt(
    const __hip_bfloat16* __restrict__ A, const __hip_bfloat16* __restrict__ B,
    const float* __restrict__ bias, void* __restrict__ C,
    int M, int N, int K) {
  __shared__ char lds[32768];  // As[128][64] bf16 | Bs[128][64] bf16
  const int tid  = threadIdx.x;
  const int w    = tid >> 6;
  const int lane = tid & 63;
  const int g    = lane >> 4;
  const int ln   = lane & 15;
  const int bm = blockIdx.y, bn = blockIdx.x;
  const int wm = (w >> 1) * 64, wn = (w & 1) * 64;

  f32x4 acc[4][4];
#pragma unroll
  for (int m = 0; m < 4; m++)
#pragma unroll
    for (int n = 0; n < 4; n++) acc[m][n] = (f32x4){0.f, 0.f, 0.f, 0.f};

  const int r8  = lane >> 3;        // row within 8-row group
  const int c16 = (lane & 7) * 16;  // byte offset along k
  const char* gA = (const char*)A + (size_t)(bm * 128 + w * 32 + r8) * K * 2 + c16;
  const char* gB = (const char*)B + (size_t)(bn * 128 + w * 32 + r8) * K * 2 + c16;
  char* lA = lds + (w * 32) * 128;
  char* lB = lds + 16384 + (w * 32) * 128;

  for (int k0 = 0; k0 < K; k0 += 64) {
#pragma unroll
    for (int i = 0; i < 4; i++) {
      gload_lds16(gA + (size_t)i * 8 * K * 2 + (size_t)k0 * 2, lA + i * 8 * 128);
      gload_lds16(gB + (size_t)i * 8 * K * 2 + (size_t)k0 * 2, lB + i * 8 * 128);
    }
    __syncthreads();
#pragma unroll
    for (int kk = 0; kk < 2; kk++) {
      bf16x8 af[4], bfr[4];
#pragma unroll
      for (int m = 0; m < 4; m++)
        af[m] = *(const bf16x8*)(lds + (wm + m * 16 + ln) * 128 + kk * 64 + g * 16);
#pragma unroll
      for (int n = 0; n < 4; n++)
        bfr[n] = *(const bf16x8*)(lds + 16384 + (wn + n * 16 + ln) * 128 + kk * 64 + g * 16);
#pragma unroll
      for (int m = 0; m < 4; m++)
#pragma unroll
        for (int n = 0; n < 4; n++)
          acc[m][n] = __builtin_amdgcn_mfma_f32_16x16x32_bf16(af[m], bfr[n], acc[m][n], 0, 0, 0);
    }
    __syncthreads();
  }

#pragma unroll
  for (int n = 0; n < 4; n++) {
    const int col = bn * 128 + wn + n * 16 + ln;
    const float bv = bias[col];
#pragma unroll
    for (int m = 0; m < 4; m++) {
      const int row0 = bm * 128 + wm + m * 16 + g * 4;
#pragma unroll
      for (int r = 0; r < 4; r++) {
        float v = acc[m][n][r] + bv;
        if (OUTF32)
          ((float*)C)[(size_t)(row0 + r) * N + col] = v;
        else
          ((__hip_bfloat16*)C)[(size_t)(row0 + r) * N + col] = __float2bfloat16(v);
      }
    }
  }
}

// ---------------- V[b,s,h,d] -> Vt[b,h,d,s] ----------------
__global__ __launch_bounds__(256) void transpose_v(const __hip_bfloat16* __restrict__ V,
                                                   __hip_bfloat16* __restrict__ Vt) {
  __shared__ unsigned short t[64 * 132];  // [s][d] padded
  const int tid = threadIdx.x;
  const int bh = blockIdx.y;
  const int b = bh >> 4, h = bh & 15;
  const int s0 = blockIdx.x * 64;
  const unsigned short* Vp = (const unsigned short*)V + (size_t)b * S_LEN * HDIM + h * HD;
#pragma unroll
  for (int i = 0; i < 4; i++) {
    int idx = i * 256 + tid;
    int s = idx >> 4, c = idx & 15;
    const uint64_t* src = (const uint64_t*)(Vp + (size_t)(s0 + s) * HDIM + c * 8);
    uint64_t v0 = src[0], v1 = src[1];
    uint64_t* dst = (uint64_t*)&t[s * 132 + c * 8];
    dst[0] = v0; dst[1] = v1;
  }
  __syncthreads();
  unsigned short* Vtp = (unsigned short*)Vt + (size_t)bh * HD * S_LEN;
#pragma unroll
  for (int i = 0; i < 8; i++) {
    int idx = i * 256 + tid;
    int d = idx >> 4, sc = idx & 15;
    u16x4 vv;
    vv.x = t[(sc * 4 + 0) * 132 + d];
    vv.y = t[(sc * 4 + 1) * 132 + d];
    vv.z = t[(sc * 4 + 2) * 132 + d];
    vv.w = t[(sc * 4 + 3) * 132 + d];
    *(u16x4*)(Vtp + (size_t)d * S_LEN + s0 + sc * 4) = vv;
  }
}

// ---------------- causal flash attention (LDS-staged, double-buffered) ----------------
// Q,K: [B,S,H] bf16 (H = nh*hd).  Vt: [B*nh, hd, S] bf16.  O: [B,S,H] bf16.
// LDS map: K0 [0,16K) K1 [16K,32K) | V0 [32K,48K) V1 [48K,64K) | P [64K,80K)
// K tile: 64 rows x 256B, chunk swizzle c ^= row&7 (16B chunks).
// V tile: 128 rows x 128B, chunk swizzle c ^= row&7 (16B chunks).
#define ATT_SCALE 0.08838834764831845f
#define L2E 1.4426950408889634f

__global__ __launch_bounds__(256, 2) void attn_kernel(
    const __hip_bfloat16* __restrict__ Q, const __hip_bfloat16* __restrict__ Kg,
    const __hip_bfloat16* __restrict__ Vt, __hip_bfloat16* __restrict__ O) {
  __shared__ char lds[81920];
  const int tid = threadIdx.x;
  const int w = tid >> 6;
  const int lane = tid & 63;
  const int g = lane >> 4;
  const int ln = lane & 15;
  const int qt = 15 - blockIdx.x;   // heavy q-tiles dispatched first
  const int bh = blockIdx.y;
  const int b = bh >> 4, h = bh & 15;
  const int q0 = qt * 128 + w * 32;  // this wave's first q row

  const char* Qb = (const char*)Q + ((size_t)b * S_LEN * HDIM + h * HD) * 2;
  const char* Kb = (const char*)Kg + ((size_t)b * S_LEN * HDIM + h * HD) * 2;
  const char* Vb = (const char*)Vt + ((size_t)bh * HD * S_LEN) * 2;
  char* pw = lds + 65536 + w * 4096;

  // staging lane decomposition
  const int kr = lane >> 4;   // K: row within 4-row group
  const int kc = lane & 15;   // K: 16B chunk 0..15
  const int vr = lane >> 3;   // V: row within 8-row group (= row&7)
  const int vc = lane & 7;    // V: 16B chunk 0..7

  // Q fragments in registers: qf[qs][dc] covers rows q0+qs*16+ln, d = dc*32+g*8..+7
  bf16x8 qf[2][4];
#pragma unroll
  for (int qs = 0; qs < 2; qs++)
#pragma unroll
    for (int dc = 0; dc < 4; dc++)
      qf[qs][dc] = *(const bf16x8*)(Qb + (size_t)(q0 + qs * 16 + ln) * HDIM * 2 +
                                    (dc * 32 + g * 8) * 2);

  f32x4 o[2][8];
#pragma unroll
  for (int qs = 0; qs < 2; qs++)
#pragma unroll
    for (int ds = 0; ds < 8; ds++) o[qs][ds] = (f32x4){0.f, 0.f, 0.f, 0.f};
  float mrun[2][4], lrun[2][4];
#pragma unroll
  for (int qs = 0; qs < 2; qs++)
#pragma unroll
    for (int r = 0; r < 4; r++) { mrun[qs][r] = -__builtin_inff(); lrun[qs][r] = 0.f; }

  // ---- staging: all 4 waves cooperatively load one K tile + one V tile ----
  auto stage = [&](int buf, int kv0) {
    char* kb = lds + buf * 16384;
    char* vb = lds + 32768 + buf * 16384;
#pragma unroll
    for (int i = 0; i < 4; i++) {
      int r = w * 16 + i * 4 + kr;  // K row 0..63
      gload_lds16(Kb + (size_t)(kv0 + r) * (HDIM * 2) + ((kc ^ (r & 7)) << 4),
                  kb + (w * 16 + i * 4) * 256);
    }
#pragma unroll
    for (int i = 0; i < 4; i++) {
      int r = w * 32 + i * 8 + vr;  // V row (d) 0..127; r&7 == vr
      gload_lds16(Vb + (size_t)r * (S_LEN * 2) + (size_t)kv0 * 2 + ((vc ^ vr) << 4),
                  vb + (w * 32 + i * 8) * 128);
    }
  };

  const int nt = 2 * qt + 2;  // block-uniform kv tile count (causal)
  stage(0, 0);
  __syncthreads();

  for (int t = 0; t < nt; t++) {
    const int kv0 = t * 64;
    if (t + 1 < nt) stage((t + 1) & 1, kv0 + 64);
    const char* kbuf = lds + (t & 1) * 16384;
    const char* vbuf = lds + 32768 + (t & 1) * 16384;

    // ---- S = Q K^T ----
    f32x4 sa[2][4];
#pragma unroll
    for (int qs = 0; qs < 2; qs++)
#pragma unroll
      for (int ks = 0; ks < 4; ks++) sa[qs][ks] = (f32x4){0.f, 0.f, 0.f, 0.f};
#pragma unroll
    for (int dc = 0; dc < 4; dc++) {
      bf16x8 kf[4];
#pragma unroll
      for (int ks = 0; ks < 4; ks++)
        kf[ks] = *(const bf16x8*)(kbuf + (ks * 16 + ln) * 256 +
                                  (((dc * 4 + g) ^ (ln & 7)) << 4));
#pragma unroll
      for (int qs = 0; qs < 2; qs++)
#pragma unroll
        for (int ks = 0; ks < 4; ks++)
          sa[qs][ks] = __builtin_amdgcn_mfma_f32_16x16x32_bf16(qf[qs][dc], kf[ks], sa[qs][ks], 0, 0, 0);
    }
    // ---- scale + causal mask ----
    const bool needmask = (kv0 + 63) > q0;
#pragma unroll
    for (int qs = 0; qs < 2; qs++)
#pragma unroll
      for (int ks = 0; ks < 4; ks++)
#pragma unroll
        for (int r = 0; r < 4; r++) {
          float s = sa[qs][ks][r] * ATT_SCALE;
          if (needmask && (kv0 + ks * 16 + ln) > (q0 + qs * 16 + g * 4 + r))
            s = -__builtin_inff();
          sa[qs][ks][r] = s;
        }
    // ---- online softmax ----
    float alpha[2][4];
#pragma unroll
    for (int qs = 0; qs < 2; qs++)
#pragma unroll
      for (int r = 0; r < 4; r++) {
        float mx = fmaxf(fmaxf(sa[qs][0][r], sa[qs][1][r]), fmaxf(sa[qs][2][r], sa[qs][3][r]));
        mx = fmaxf(mx, __shfl_xor(mx, 1));
        mx = fmaxf(mx, __shfl_xor(mx, 2));
        mx = fmaxf(mx, __shfl_xor(mx, 4));
        mx = fmaxf(mx, __shfl_xor(mx, 8));
        float mnew = fmaxf(mrun[qs][r], mx);
        alpha[qs][r] = exp2f((mrun[qs][r] - mnew) * L2E);
        mrun[qs][r] = mnew;
      }
    float rsum[2][4];
#pragma unroll
    for (int qs = 0; qs < 2; qs++)
#pragma unroll
      for (int r = 0; r < 4; r++) rsum[qs][r] = 0.f;
#pragma unroll
    for (int qs = 0; qs < 2; qs++)
#pragma unroll
      for (int ks = 0; ks < 4; ks++)
#pragma unroll
        for (int r = 0; r < 4; r++) {
          float p = exp2f((sa[qs][ks][r] - mrun[qs][r]) * L2E);
          sa[qs][ks][r] = p;
          rsum[qs][r] += p;
        }
#pragma unroll
    for (int qs = 0; qs < 2; qs++)
#pragma unroll
      for (int r = 0; r < 4; r++) {
        float rs = rsum[qs][r];
        rs += __shfl_xor(rs, 1);
        rs += __shfl_xor(rs, 2);
        rs += __shfl_xor(rs, 4);
        rs += __shfl_xor(rs, 8);
        lrun[qs][r] = lrun[qs][r] * alpha[qs][r] + rs;
      }
    // ---- rescale O ----
#pragma unroll
    for (int qs = 0; qs < 2; qs++)
#pragma unroll
      for (int ds = 0; ds < 8; ds++)
#pragma unroll
        for (int r = 0; r < 4; r++) o[qs][ds][r] *= alpha[qs][r];
    // ---- P -> LDS (bf16, XOR swizzle: chunk ^= row&7) ----
#pragma unroll
    for (int qs = 0; qs < 2; qs++)
#pragma unroll
      for (int ks = 0; ks < 4; ks++)
#pragma unroll
        for (int r = 0; r < 4; r++) {
          int row = qs * 16 + g * 4 + r;
          int key = ks * 16 + ln;
          *(__hip_bfloat16*)(pw + row * 128 + (((key >> 3) ^ (row & 7)) << 4) + (key & 7) * 2) =
              __float2bfloat16(sa[qs][ks][r]);
        }
    // ---- O += P V ----
#pragma unroll
    for (int kk = 0; kk < 2; kk++) {
      bf16x8 pa[2];
#pragma unroll
      for (int qs = 0; qs < 2; qs++) {
        int row = qs * 16 + ln;
        pa[qs] = *(const bf16x8*)(pw + row * 128 + (((kk * 4 + g) ^ (row & 7)) << 4));
      }
#pragma unroll
      for (int ds = 0; ds < 8; ds++) {
        bf16x8 vf = *(const bf16x8*)(vbuf + (ds * 16 + ln) * 128 +
                                     (((kk * 4 + g) ^ (ln & 7)) << 4));
#pragma unroll
        for (int qs = 0; qs < 2; qs++)
          o[qs][ds] = __builtin_amdgcn_mfma_f32_16x16x32_bf16(pa[qs], vf, o[qs][ds], 0, 0, 0);
      }
    }
    __syncthreads();
  }
  // ---- epilogue ----
  float inv[2][4];
#pragma unroll
  for (int qs = 0; qs < 2; qs++)
#pragma unroll
    for (int r = 0; r < 4; r++) inv[qs][r] = 1.0f / lrun[qs][r];
  __hip_bfloat16* Ob = O + (size_t)b * S_LEN * HDIM + h * HD;
#pragma unroll
  for (int qs = 0; qs < 2; qs++)
#pragma unroll
    for (int ds = 0; ds < 8; ds++)
#pragma unroll
      for (int r = 0; r < 4; r++)
        Ob[(size_t)(q0 + qs * 16 + g * 4 + r) * HDIM + ds * 16 + ln] =
            __float2bfloat16(o[qs][ds][r] * inv[qs][r]);
}

extern "C" void kernel_launch(void* const* d_in, const int* in_sizes, int n_in,
                              void* d_out, int out_size, void* d_ws, size_t ws_size,
                              hipStream_t stream) {
  const float* X  = (const float*)d_in[0];
  const float* Wq = (const float*)d_in[2];
  const float* bq = (const float*)d_in[3];
  const float* Wk = (const float*)d_in[4];
  const float* bk = (const float*)d_in[5];
  const float* Wv = (const float*)d_in[6];
  const float* bv = (const float*)d_in[7];
  const float* Wo = (const float*)d_in[8];
  const float* bo = (const float*)d_in[9];

  char* ws = (char*)d_ws;
  __hip_bfloat16* Xb   = (__hip_bfloat16*)(ws);                 // 32 MB
  __hip_bfloat16* Wqb  = (__hip_bfloat16*)(ws + 33554432);      // 8 MB
  __hip_bfloat16* Wkb  = (__hip_bfloat16*)(ws + 41943040);      // 8 MB
  __hip_bfloat16* Wvb  = (__hip_bfloat16*)(ws + 50331648);      // 8 MB
  __hip_bfloat16* Wob  = (__hip_bfloat16*)(ws + 58720256);      // 8 MB
  __hip_bfloat16* Qb   = (__hip_bfloat16*)(ws + 67108864);      // 32 MB
  __hip_bfloat16* Kb   = (__hip_bfloat16*)(ws + 100663296);     // 32 MB
  __hip_bfloat16* Vbuf = (__hip_bfloat16*)(ws + 134217728);     // 32 MB (reused as attn out)
  __hip_bfloat16* Vtb  = (__hip_bfloat16*)(ws + 167772160);     // 32 MB -> total 192 MB
  __hip_bfloat16* Ob   = Vbuf;

  cvt_kernel<<<2048, 256, 0, stream>>>(X,  (unsigned short*)Xb,  16777216 / 4);
  cvt_kernel<<<512,  256, 0, stream>>>(Wq, (unsigned short*)Wqb, 4194304 / 4);
  cvt_kernel<<<512,  256, 0, stream>>>(Wk, (unsigned short*)Wkb, 4194304 / 4);
  cvt_kernel<<<512,  256, 0, stream>>>(Wv, (unsigned short*)Wvb, 4194304 / 4);
  cvt_kernel<<<512,  256, 0, stream>>>(Wo, (unsigned short*)Wob, 4194304 / 4);

  dim3 gg(16, 64);  // (N/128, M/128)
  gemm_bt<0><<<gg, 256, 0, stream>>>(Xb, Wqb, bq, Qb,   8192, 2048, 2048);
  gemm_bt<0><<<gg, 256, 0, stream>>>(Xb, Wkb, bk, Kb,   8192, 2048, 2048);
  gemm_bt<0><<<gg, 256, 0, stream>>>(Xb, Wvb, bv, Vbuf, 8192, 2048, 2048);

  transpose_v<<<dim3(32, 64), 256, 0, stream>>>(Vbuf, Vtb);

  attn_kernel<<<dim3(16, 64), 256, 0, stream>>>(Qb, Kb, Vtb, Ob);

  gemm_bt<1><<<gg, 256, 0, stream>>>(Ob, Wob, bo, (float*)d_out, 8192, 2048, 2048);
}